// Round 4
// baseline (101.744 us; speedup 1.0000x reference)
//
#include <hip/hip_runtime.h>
#include <hip/hip_bf16.h>

// out[b, :] = (1/K) * sum_k embed[ids[b,k], :]
// B=8192, K=32, D=128, V=100000.
//
// R4: the harness re-poisons 260MB before every timed replay -> L2/L3 hold
// none of the 51MB table; every gather line is a cold ~900cyc HBM miss and
// the per-CU outstanding-miss window (~16 lines) caps random service at
// ~2.3 B/cyc/CU = 1.4 TB/s -> the invariant 96us across R1-R3.
// Fix: phase A streams the whole table coalesced (grid-stride float4, ~9us,
// full row-buffer efficiency) to pull it into L3/L2; phase B gathers from
// warm cache at ~2x+ the service rate (latency-bound: rate ~ Q*line/latency).

#define K_NEIGH 32
#define D2      64   // D/2 float2 chunks per row
#define ROWS_PER_BLOCK 4
#define BATCH 16

__global__ __launch_bounds__(256, 4) void mean_agg_kernel(
    const int* __restrict__ ids,        // [B, K] int32
    const float2* __restrict__ embed,   // [V, D/2] float2
    float2* __restrict__ out,           // [B, D/2] float2
    float* __restrict__ ws,             // dummy sink (never actually written)
    int table_f4)                       // V*D/4 float4 chunks
{
    // ---- Phase A: sequential warm-up sweep of the embed table ----
    const float4* __restrict__ tab = (const float4*)embed;
    float dummy = 0.f;
    {
        const int tstride = gridDim.x * blockDim.x;
        for (int i = blockIdx.x * blockDim.x + threadIdx.x; i < table_f4; i += tstride) {
            const float4 t = tab[i];
            dummy += t.x + t.y + t.z + t.w;
        }
    }

    // ---- Phase B: gather from (now warm) cache ----
    const int lane = threadIdx.x & 63;
    int row = blockIdx.x * ROWS_PER_BLOCK + (threadIdx.x >> 6);
    row = __builtin_amdgcn_readfirstlane(row);   // wave-uniform -> SGPR ids

    const int* __restrict__ rowids = ids + row * K_NEIGH;
    int sid[K_NEIGH];
#pragma unroll
    for (int k = 0; k < K_NEIGH; ++k) sid[k] = rowids[k];

    float2 acc = make_float2(0.f, 0.f);

#pragma unroll
    for (int half = 0; half < K_NEIGH / BATCH; ++half) {
        float2 v[BATCH];
#pragma unroll
        for (int j = 0; j < BATCH; ++j) {
            const int id = sid[half * BATCH + j];
            v[j] = embed[(long)id * D2 + lane];
        }
#pragma unroll
        for (int j = 0; j < BATCH; ++j) {
            acc.x += v[j].x;
            acc.y += v[j].y;
        }
    }

    const float s = 1.0f / (float)K_NEIGH;
    out[row * D2 + lane] = make_float2(acc.x * s, acc.y * s);

    // Keep phase A's loads alive (random-normal data: condition never true,
    // but the compiler can't prove it).
    if (dummy == 1.0e38f) ws[0] = dummy;
}

extern "C" void kernel_launch(void* const* d_in, const int* in_sizes, int n_in,
                              void* d_out, int out_size, void* d_ws, size_t ws_size,
                              hipStream_t stream) {
    const int*    ids   = (const int*)d_in[0];      // [B, K] int32
    const float2* embed = (const float2*)d_in[1];   // [V, D/2]
    float2*       out   = (float2*)d_out;           // [B, D/2]
    const int table_f4  = in_sizes[1] / 4;          // V*D/4 float4 chunks

    const int B = 8192;
    dim3 grid(B / ROWS_PER_BLOCK);
    dim3 block(256);
    mean_agg_kernel<<<grid, block, 0, stream>>>(ids, embed, out, (float*)d_ws, table_f4);
}

// Round 5
// 96.121 us; speedup vs baseline: 1.0585x; 1.0585x over previous
//
#include <hip/hip_runtime.h>
#include <hip/hip_bf16.h>

// out[b, :] = (1/K) * sum_k embed[ids[b,k], :]
// B=8192, K=32, D=128, V=100000.
//
// R5: persistent-block test. R1-R4 (MLP depth 1..32, occupancy 8..32 waves/CU,
// cold vs warmed L3) were ALL ~96us -> gather rate is invariant to memory tier
// and per-wave MLP. R2's OccupancyPercent=2.7% (~0.9 waves/CU resident) points
// at block-churn/residency as the shared bottleneck: 2048 single-shot blocks
// entering at ~21/us. Fix under test: 512 persistent blocks (2/CU), each wave
// processes 4 rows via grid-stride; per row all 32 float2 gathers issue
// before draining (64 VGPR destinations, SGPR-based addressing, no shfl).

#define K_NEIGH 32
#define D2      64            // D/2 float2 chunks per row
#define NBLOCKS 512
#define WAVES_PER_BLOCK 4     // 256 threads
#define TOTAL_WAVES (NBLOCKS * WAVES_PER_BLOCK)   // 2048
#define B_ROWS 8192
#define ROWS_PER_WAVE (B_ROWS / TOTAL_WAVES)      // 4

__global__ __launch_bounds__(256, 4) void mean_agg_kernel(
    const int* __restrict__ ids,        // [B, K] int32
    const float2* __restrict__ embed,   // [V, D/2] float2
    float2* __restrict__ out)           // [B, D/2] float2
{
    const int lane = threadIdx.x & 63;
    const int wave_g = blockIdx.x * WAVES_PER_BLOCK + (threadIdx.x >> 6);

#pragma unroll
    for (int r = 0; r < ROWS_PER_WAVE; ++r) {
        int row = wave_g + r * TOTAL_WAVES;       // grid-stride over rows
        row = __builtin_amdgcn_readfirstlane(row);

        // Wave-uniform scalar id fetch (s_load_dwordx8 x4 expected).
        const int* __restrict__ rowids = ids + row * K_NEIGH;
        int sid[K_NEIGH];
#pragma unroll
        for (int k = 0; k < K_NEIGH; ++k) sid[k] = rowids[k];

        // Issue ALL 32 gathers before draining: 32 independent
        // global_load_dwordx2, 64 VGPRs of destinations in flight.
        float2 v[K_NEIGH];
#pragma unroll
        for (int k = 0; k < K_NEIGH; ++k) {
            v[k] = embed[(long)sid[k] * D2 + lane];
        }

        float2 acc = make_float2(0.f, 0.f);
#pragma unroll
        for (int k = 0; k < K_NEIGH; ++k) {
            acc.x += v[k].x;
            acc.y += v[k].y;
        }

        const float s = 1.0f / (float)K_NEIGH;
        out[row * D2 + lane] = make_float2(acc.x * s, acc.y * s);
    }
}

extern "C" void kernel_launch(void* const* d_in, const int* in_sizes, int n_in,
                              void* d_out, int out_size, void* d_ws, size_t ws_size,
                              hipStream_t stream) {
    const int*    ids   = (const int*)d_in[0];      // [B, K] int32
    const float2* embed = (const float2*)d_in[1];   // [V, D/2]
    float2*       out   = (float2*)d_out;           // [B, D/2]

    dim3 grid(NBLOCKS);
    dim3 block(256);
    mean_agg_kernel<<<grid, block, 0, stream>>>(ids, embed, out);
}